// Round 3
// baseline (202.449 us; speedup 1.0000x reference)
//
#include <hip/hip_runtime.h>

typedef short bf16x8 __attribute__((ext_vector_type(8)));
typedef float f32x16 __attribute__((ext_vector_type(16)));

constexpr int S = 2048;
constexpr int H = 16;
constexpr int D = 128;
constexpr int BM = 128;    // q rows per phase (4 waves x 32)
constexpr int TILE = 8192; // shorts per 64-row K/V tile (16 KB)
constexpr int KSTR = 136;  // prepass staging LDS stride (shorts)

// ---------------------------------------------------------------------------
// Workspace tile layouts (per (b,h), 32 tiles of 16KB, fully linear for DMA):
//  K tile: 8 groups of 2KB; group g = rows 8g..8g+7. 16B-slot within group:
//     slot(rho,c) = rho*16 + (c ^ rho), rho = row&7, c = d-chunk 0..15.
//  V tile: [d][sigma], sigma(k) = k with bits 2<->3 swapped; 16 groups of 1KB
//     (8 d-rows), slot(rho,cc) = rho*8 + (cc ^ rho).  sigma makes 8 contiguous
//     shorts a valid MFMA A-operand matching the B-operand built by packing
//     exp(S^T) regs pairwise.  P never touches LDS.
//
// fa_fwd v3 (qpair schedule): 256 blocks, each does q-tiles (qp, 15-qp)
// sequentially = EXACTLY 34 KV-tiles per block -> perfect static balance,
// 1 block/CU (96KB LDS enforces it).  Triple-buffered staging with counted
// vmcnt(8) (never 0 mid-loop) -> load latency spans ~2 compute iterations.
// Epilogue stores O directly from registers (lane = q-row in O^T layout).
// ---------------------------------------------------------------------------

__device__ inline unsigned int pk2(float a, float b) {
    // pack 2 f32 -> 2 bf16 (RNE bit-trick; finite values only). low=a, high=b
    unsigned int ua = __builtin_bit_cast(unsigned int, a);
    unsigned int ub = __builtin_bit_cast(unsigned int, b);
    ua += 0x7fffu + ((ua >> 16) & 1u);
    ub += 0x7fffu + ((ub >> 16) & 1u);
    return (ua >> 16) | (ub & 0xffff0000u);
}

__device__ __forceinline__ void gld16(const unsigned short* g, unsigned short* l) {
    __builtin_amdgcn_global_load_lds(
        (const __attribute__((address_space(1))) unsigned int*)g,
        (__attribute__((address_space(3))) unsigned int*)l, 16, 0, 0);
}

// ---- fused prepass: K -> permuted bf16 tiles; V -> transposed+sigma tiles ----
__global__ __launch_bounds__(256) void cvt_kv(const float* __restrict__ K,
                                              const float* __restrict__ V,
                                              unsigned short* __restrict__ Kb,
                                              unsigned short* __restrict__ Vtb) {
    __shared__ unsigned short Vl[64 * KSTR];
    const int tid = threadIdx.x;
    const int t   = blockIdx.x;   // 64-row tile
    const int bh  = blockIdx.y;
    const int b = bh >> 4, h = bh & 15;
    const size_t base = ((size_t)(b * S + t * 64) * H + h) * D;

    // --- K: pack into permuted slots, contiguous dest ---
    unsigned short* outK = Kb + ((size_t)bh * 32 + t) * TILE;
    #pragma unroll
    for (int u = 0; u < 4; ++u) {
        const int dlin = u * 256 + tid;            // dest 16B-slot 0..1023
        const int grp = dlin >> 7;
        const int s   = dlin & 127;
        const int rho = s >> 4;
        const int c   = (s & 15) ^ rho;            // involution
        const float* p = K + base + (size_t)(grp * 8 + rho) * (H * D) + c * 8;
        float4 f0 = *(const float4*)p;
        float4 f1 = *(const float4*)(p + 4);
        unsigned int w[4];
        w[0] = pk2(f0.x, f0.y); w[1] = pk2(f0.z, f0.w);
        w[2] = pk2(f1.x, f1.y); w[3] = pk2(f1.z, f1.w);
        *(uint4*)(outK + dlin * 8) = *(const uint4*)w;
    }

    // --- V: stage rows to LDS ---
    #pragma unroll
    for (int u = 0; u < 4; ++u) {
        const int cidx = tid + 256 * u;
        const int n    = cidx >> 4;
        const int off  = (cidx & 15) * 8;
        const float* p = V + base + (size_t)n * (H * D) + off;
        float4 f0 = *(const float4*)p;
        float4 f1 = *(const float4*)(p + 4);
        unsigned int w[4];
        w[0] = pk2(f0.x, f0.y); w[1] = pk2(f0.z, f0.w);
        w[2] = pk2(f1.x, f1.y); w[3] = pk2(f1.z, f1.w);
        *(uint4*)&Vl[n * KSTR + off] = *(const uint4*)w;
    }
    __syncthreads();

    // --- transpose: dest col sigma holds source row k = sigma-bitswap(2,3) ---
    const int d  = tid >> 1;
    const int kh = (tid & 1) * 32;
    unsigned short tmp[32];
    #pragma unroll
    for (int m = 0; m < 32; ++m) {
        const int sig = kh + m;
        const int k = (sig & ~12) | ((sig & 4) << 1) | ((sig & 8) >> 1);
        tmp[m] = Vl[k * KSTR + d];
    }
    unsigned short* outV = Vtb + ((size_t)bh * 32 + t) * TILE;
    const int g = d >> 3, rho = d & 7;
    #pragma unroll
    for (int uu = 0; uu < 4; ++uu) {
        const int cc = (kh >> 3) + uu;
        *(uint4*)(outV + g * 512 + (rho * 8 + (cc ^ rho)) * 8) = *(const uint4*)&tmp[uu * 8];
    }
}

__global__ __launch_bounds__(256, 1) void fa_fwd(
    const float* __restrict__ Q,
    const unsigned short* __restrict__ Kb,
    const unsigned short* __restrict__ Vtb,
    const int* __restrict__ causal_p,
    float* __restrict__ Op)
{
    __shared__ unsigned short Kl[3][TILE];   // 48 KB
    __shared__ unsigned short Vl[3][TILE];   // 48 KB  (96 KB total -> 1 block/CU)

    const int tid  = threadIdx.x;
    const int wave = tid >> 6;
    const int lane = tid & 63;
    const int ln   = lane & 31;
    const int half = lane >> 5;

    // XCD-pinned remap (4 bh per XCD -> K/V workspace L2-resident).
    int bh, qp;
    if (gridDim.x == 8 && gridDim.y == 32) {
        const int lid = blockIdx.x + (blockIdx.y << 3);
        const int xcd = lid & 7;
        const int ii  = lid >> 3;             // 0..31
        bh = (xcd << 2) + (ii & 3);
        qp = ii >> 2;                         // 0..7
    } else {
        bh = blockIdx.y;
        qp = blockIdx.x;
    }
    const int b = bh >> 4;
    const int h = bh & 15;
    const int causal = *causal_p;
    const float cfold = 0.12751743f;  // (1/sqrt(D)) * log2(e), folded into Q

    const unsigned short* Ksrc = Kb  + (size_t)bh * (32 * TILE);
    const unsigned short* Vsrc = Vtb + (size_t)bh * (32 * TILE);
    const int sg   = wave * 4;        // this wave's 4 staging groups
    const int loff = lane * 8;        // shorts: lane*16B within a 1KB group

    // loop-invariant permuted read addressing
    const int kb   = (ln >> 3) * 1024 + (ln & 7) * 128;  // shorts
    const int krho = ln & 7;
    const int vg   = (ln >> 3) * 512;                    // shorts
    const int vrho = ln & 7;

    #pragma unroll 1
    for (int ph = 0; ph < 2; ++ph) {
        const int qblk  = ph ? (15 - qp) : qp;   // pair sums to 34 tiles
        const int q0    = qblk * BM;
        const int qrow0 = q0 + wave * 32;
        const int jmax  = causal ? ((q0 + BM - 1) >> 6) : (S / 64 - 1);  // >= 1

        // ---- Q fragments (B-operand; lane = q col), pre-scaled ----
        bf16x8 qf[8];
        {
            const size_t rowoff = ((size_t)(b * S + qrow0 + ln) * H + h) * D;
            #pragma unroll
            for (int c = 0; c < 8; ++c) {
                float4 f0 = *(const float4*)(Q + rowoff + c * 16 + half * 8);
                float4 f1 = *(const float4*)(Q + rowoff + c * 16 + half * 8 + 4);
                unsigned int t[4];
                t[0] = pk2(f0.x * cfold, f0.y * cfold);
                t[1] = pk2(f0.z * cfold, f0.w * cfold);
                t[2] = pk2(f1.x * cfold, f1.y * cfold);
                t[3] = pk2(f1.z * cfold, f1.w * cfold);
                qf[c] = *(const bf16x8*)t;
            }
        }

        // ---- prologue: stage tiles 0 and 1 (jmax >= 1 always) ----
        #pragma unroll
        for (int qq = 0; qq < 4; ++qq) {
            gld16(Ksrc + (sg + qq) * 512 + loff, &Kl[0][(sg + qq) * 512]);
            gld16(Vsrc + (sg + qq) * 512 + loff, &Vl[0][(sg + qq) * 512]);
        }
        #pragma unroll
        for (int qq = 0; qq < 4; ++qq) {
            gld16(Ksrc + TILE + (sg + qq) * 512 + loff, &Kl[1][(sg + qq) * 512]);
            gld16(Vsrc + TILE + (sg + qq) * 512 + loff, &Vl[1][(sg + qq) * 512]);
        }
        asm volatile("s_waitcnt vmcnt(8)" ::: "memory");   // tile 0 landed
        __builtin_amdgcn_s_barrier();

        f32x16 o[4];
        #pragma unroll
        for (int dt = 0; dt < 4; ++dt)
            #pragma unroll
            for (int r = 0; r < 16; ++r) o[dt][r] = 0.0f;
        float l = 0.0f;

        int cur = 0;
        #pragma unroll 1
        for (int j = 0; j <= jmax; ++j) {
            // ---- stage tile j+2 into the free buffer (depth-2 pipeline) ----
            const bool pf2 = (j + 2 <= jmax);
            if (pf2) {
                int nxt = cur + 2; if (nxt >= 3) nxt -= 3;
                const unsigned short* ks = Ksrc + (size_t)(j + 2) * TILE;
                const unsigned short* vs = Vsrc + (size_t)(j + 2) * TILE;
                #pragma unroll
                for (int qq = 0; qq < 4; ++qq) {
                    gld16(ks + (sg + qq) * 512 + loff, &Kl[nxt][(sg + qq) * 512]);
                    gld16(vs + (sg + qq) * 512 + loff, &Vl[nxt][(sg + qq) * 512]);
                }
            }

            // wave-uniform skip of fully-masked diagonal tiles
            const bool active = (!causal) || (j * 64 <= qrow0 + 31);
            if (active) {
                const unsigned short* Klc = Kl[cur];
                const unsigned short* Vtc = Vl[cur];

                // ---- S^T = K Q^T: lane = q col, k rows in regs ----
                f32x16 sacc[2];
                #pragma unroll
                for (int nt = 0; nt < 2; ++nt) {
                    #pragma unroll
                    for (int r = 0; r < 16; ++r) sacc[nt][r] = 0.0f;
                    const unsigned short* kl = Klc + nt * 4096 + kb;
                    #pragma unroll
                    for (int c = 0; c < 8; ++c) {
                        uint4 raw = *(const uint4*)(kl + (((2 * c + half) ^ krho) << 3));
                        bf16x8 kf = *(const bf16x8*)&raw;
                        sacc[nt] = __builtin_amdgcn_mfma_f32_32x32x16_bf16(kf, qf[c], sacc[nt], 0, 0, 0);
                    }
                }

                // ---- in-register softmax numerator (no max-subtraction) ----
                float p[32];
                const int thr  = qrow0 + ln - j * 64;  // k_local <= thr allowed
                const bool full = (!causal) || (j * 64 + 63 <= qrow0);
                #pragma unroll
                for (int nt = 0; nt < 2; ++nt)
                    #pragma unroll
                    for (int r = 0; r < 16; ++r) {
                        float e = __builtin_amdgcn_exp2f(sacc[nt][r]);
                        if (!full) {
                            const int kl_ = nt * 32 + (r & 3) + 8 * (r >> 2) + 4 * half;
                            if (kl_ > thr) e = 0.0f;
                        }
                        l += e;
                        p[nt * 16 + r] = e;
                    }

                // ---- O^T += V^T P: pack P pairwise -> B-operand ----
                #pragma unroll
                for (int win = 0; win < 4; ++win) {
                    unsigned int pw[4];
                    #pragma unroll
                    for (int d2 = 0; d2 < 4; ++d2)
                        pw[d2] = pk2(p[win * 8 + 2 * d2], p[win * 8 + 2 * d2 + 1]);
                    bf16x8 pf = *(const bf16x8*)pw;
                    const int voff = ((vrho * 8) + ((win * 2 + half) ^ vrho)) << 3;
                    #pragma unroll
                    for (int dt = 0; dt < 4; ++dt) {
                        uint4 raw = *(const uint4*)(Vtc + dt * 2048 + vg + voff);
                        bf16x8 vf = *(const bf16x8*)&raw;
                        o[dt] = __builtin_amdgcn_mfma_f32_32x32x16_bf16(vf, pf, o[dt], 0, 0, 0);
                    }
                }
            }

            // counted wait: only tile j+1's stages must have landed (FIFO);
            // tile j+2's 8 loads stay in flight across the barrier.
            if (pf2) asm volatile("s_waitcnt vmcnt(8)" ::: "memory");
            else     asm volatile("s_waitcnt vmcnt(0)" ::: "memory");
            __builtin_amdgcn_s_barrier();
            cur += 1; if (cur >= 3) cur -= 3;
        }

        // ---- epilogue: direct register->global store (lane = q row) ----
        const float lt  = l + __shfl_xor(l, 32);
        const float inv = 1.0f / lt;
        float* op = Op + ((size_t)(b * S + qrow0 + ln) * H + h) * D;
        #pragma unroll
        for (int dt = 0; dt < 4; ++dt)
            #pragma unroll
            for (int rq = 0; rq < 4; ++rq) {
                float4 st;
                st.x = o[dt][rq * 4 + 0] * inv;
                st.y = o[dt][rq * 4 + 1] * inv;
                st.z = o[dt][rq * 4 + 2] * inv;
                st.w = o[dt][rq * 4 + 3] * inv;
                *(float4*)(op + dt * 32 + 8 * rq + 4 * half) = st;
            }
    }
}

extern "C" void kernel_launch(void* const* d_in, const int* in_sizes, int n_in,
                              void* d_out, int out_size, void* d_ws, size_t ws_size,
                              hipStream_t stream) {
    const int B = in_sizes[0] / (S * H * D);   // expect 2
    unsigned short* Kb  = (unsigned short*)d_ws;
    unsigned short* Vtb = Kb + (size_t)B * S * H * D;

    cvt_kv<<<dim3(S / 64, B * H), 256, 0, stream>>>(
        (const float*)d_in[1], (const float*)d_in[2], Kb, Vtb);
    fa_fwd<<<dim3(8, B * H), 256, 0, stream>>>(
        (const float*)d_in[0], Kb, Vtb, (const int*)d_in[3], (float*)d_out);
}

// Round 4
// 191.620 us; speedup vs baseline: 1.0565x; 1.0565x over previous
//
#include <hip/hip_runtime.h>

typedef short bf16x8 __attribute__((ext_vector_type(8)));
typedef float f32x16 __attribute__((ext_vector_type(16)));

constexpr int S = 2048;
constexpr int H = 16;
constexpr int D = 128;
constexpr int BM = 128;    // q rows per phase (4 q-groups x 32)
constexpr int TILE = 8192; // shorts per 64-row K/V tile (16 KB)
constexpr int KSTR = 136;  // prepass staging LDS stride (shorts)

// ---------------------------------------------------------------------------
// Workspace tile layouts (per (b,h), 32 tiles of 16KB, fully linear for DMA):
//  K tile: 8 groups of 2KB; group g = rows 8g..8g+7. 16B-slot within group:
//     slot(rho,c) = rho*16 + (c ^ rho), rho = row&7, c = d-chunk 0..15.
//  V tile: [d][sigma], sigma(k) = k with bits 2<->3 swapped; 16 groups of 1KB
//     (8 d-rows), slot(rho,cc) = rho*8 + (cc ^ rho).  sigma makes 8 contiguous
//     shorts a valid MFMA A-operand matching the B-operand built by packing
//     exp(S^T) regs pairwise.  P never touches LDS.
//
// fa_fwd v4 (8-wave k-split): 256 blocks x 512 threads, 1 block/CU (100KB LDS
// cap).  Block does q-tiles (qp, 15-qp) = exactly 34 KV-tiles.  Wave w: q-group
// qw=w&3, k-half nt=w>>2 -> per-wave work halves and 2 waves/SIMD hide each
// other's ds_read->MFMA and exp->pack chains (R3 at 1 wave/SIMD exposed them).
// O,l are k-partial; merged via LDS once per phase, then stored from regs.
// ---------------------------------------------------------------------------

__device__ inline unsigned int pk2(float a, float b) {
    // pack 2 f32 -> 2 bf16 (RNE bit-trick; finite values only). low=a, high=b
    unsigned int ua = __builtin_bit_cast(unsigned int, a);
    unsigned int ub = __builtin_bit_cast(unsigned int, b);
    ua += 0x7fffu + ((ua >> 16) & 1u);
    ub += 0x7fffu + ((ub >> 16) & 1u);
    return (ua >> 16) | (ub & 0xffff0000u);
}

__device__ __forceinline__ void gld16(const unsigned short* g, unsigned short* l) {
    __builtin_amdgcn_global_load_lds(
        (const __attribute__((address_space(1))) unsigned int*)g,
        (__attribute__((address_space(3))) unsigned int*)l, 16, 0, 0);
}

// ---- fused prepass: K -> permuted bf16 tiles; V -> transposed+sigma tiles ----
__global__ __launch_bounds__(256) void cvt_kv(const float* __restrict__ K,
                                              const float* __restrict__ V,
                                              unsigned short* __restrict__ Kb,
                                              unsigned short* __restrict__ Vtb) {
    __shared__ unsigned short Vl[64 * KSTR];
    const int tid = threadIdx.x;
    const int t   = blockIdx.x;   // 64-row tile
    const int bh  = blockIdx.y;
    const int b = bh >> 4, h = bh & 15;
    const size_t base = ((size_t)(b * S + t * 64) * H + h) * D;

    // --- K: pack into permuted slots, contiguous dest ---
    unsigned short* outK = Kb + ((size_t)bh * 32 + t) * TILE;
    #pragma unroll
    for (int u = 0; u < 4; ++u) {
        const int dlin = u * 256 + tid;            // dest 16B-slot 0..1023
        const int grp = dlin >> 7;
        const int s   = dlin & 127;
        const int rho = s >> 4;
        const int c   = (s & 15) ^ rho;            // involution
        const float* p = K + base + (size_t)(grp * 8 + rho) * (H * D) + c * 8;
        float4 f0 = *(const float4*)p;
        float4 f1 = *(const float4*)(p + 4);
        unsigned int w[4];
        w[0] = pk2(f0.x, f0.y); w[1] = pk2(f0.z, f0.w);
        w[2] = pk2(f1.x, f1.y); w[3] = pk2(f1.z, f1.w);
        *(uint4*)(outK + dlin * 8) = *(const uint4*)w;
    }

    // --- V: stage rows to LDS ---
    #pragma unroll
    for (int u = 0; u < 4; ++u) {
        const int cidx = tid + 256 * u;
        const int n    = cidx >> 4;
        const int off  = (cidx & 15) * 8;
        const float* p = V + base + (size_t)n * (H * D) + off;
        float4 f0 = *(const float4*)p;
        float4 f1 = *(const float4*)(p + 4);
        unsigned int w[4];
        w[0] = pk2(f0.x, f0.y); w[1] = pk2(f0.z, f0.w);
        w[2] = pk2(f1.x, f1.y); w[3] = pk2(f1.z, f1.w);
        *(uint4*)&Vl[n * KSTR + off] = *(const uint4*)w;
    }
    __syncthreads();

    // --- transpose: dest col sigma holds source row k = sigma-bitswap(2,3) ---
    const int d  = tid >> 1;
    const int kh = (tid & 1) * 32;
    unsigned short tmp[32];
    #pragma unroll
    for (int m = 0; m < 32; ++m) {
        const int sig = kh + m;
        const int k = (sig & ~12) | ((sig & 4) << 1) | ((sig & 8) >> 1);
        tmp[m] = Vl[k * KSTR + d];
    }
    unsigned short* outV = Vtb + ((size_t)bh * 32 + t) * TILE;
    const int g = d >> 3, rho = d & 7;
    #pragma unroll
    for (int uu = 0; uu < 4; ++uu) {
        const int cc = (kh >> 3) + uu;
        *(uint4*)(outV + g * 512 + (rho * 8 + (cc ^ rho)) * 8) = *(const uint4*)&tmp[uu * 8];
    }
}

__global__ __launch_bounds__(512, 2) void fa_fwd(
    const float* __restrict__ Q,
    const unsigned short* __restrict__ Kb,
    const unsigned short* __restrict__ Vtb,
    const int* __restrict__ causal_p,
    float* __restrict__ Op)
{
    __shared__ unsigned short Kl[2][TILE];   // 32 KB
    __shared__ unsigned short Vl[2][TILE];   // 32 KB
    __shared__ float mbf[4][64 * 36];        // 36 KB merge buffer (stride 36: conflict-free)
    __shared__ float lbf[4][32];             // l halves
    // ~101 KB total -> exactly 1 block/CU

    const int tid  = threadIdx.x;
    const int w    = tid >> 6;   // wave 0..7
    const int lane = tid & 63;
    const int ln   = lane & 31;
    const int half = lane >> 5;
    const int qw   = w & 3;      // q-group (32 rows)
    const int nt   = w >> 2;     // k-half of the 64-row KV tile

    // XCD-pinned remap (4 bh per XCD -> K/V workspace L2-resident).
    int bh, qp;
    if (gridDim.x == 8 && gridDim.y == 32) {
        const int lid = blockIdx.x + (blockIdx.y << 3);
        const int xcd = lid & 7;
        const int ii  = lid >> 3;             // 0..31
        bh = (xcd << 2) + (ii & 3);
        qp = ii >> 2;                         // 0..7
    } else {
        bh = blockIdx.y;
        qp = blockIdx.x;
    }
    const int b = bh >> 4;
    const int h = bh & 15;
    const int causal = *causal_p;
    const float cfold = 0.12751743f;  // (1/sqrt(D)) * log2(e), folded into Q

    const unsigned short* Ksrc = Kb  + (size_t)bh * (32 * TILE);
    const unsigned short* Vsrc = Vtb + (size_t)bh * (32 * TILE);
    const int sgk  = w * 2;           // this wave's 2 staging chunks (K and V)
    const int loff = lane * 8;        // shorts: lane*16B within a 1KB chunk

    // loop-invariant permuted read addressing
    const int kb   = (ln >> 3) * 1024 + (ln & 7) * 128;  // shorts (+nt*4096)
    const int krho = ln & 7;
    const int vg   = (ln >> 3) * 512;                    // shorts (+dt*2048)
    const int vrho = ln & 7;

    #pragma unroll 1
    for (int ph = 0; ph < 2; ++ph) {
        const int qblk  = ph ? (15 - qp) : qp;   // pair sums to 34 tiles
        const int q0    = qblk * BM;
        const int qrow0 = q0 + qw * 32;
        const int jmax  = causal ? ((q0 + BM - 1) >> 6) : (S / 64 - 1);

        // ---- prologue: stage tile 0 (latency hides under Q conversion) ----
        #pragma unroll
        for (int c2 = 0; c2 < 2; ++c2) {
            gld16(Ksrc + (sgk + c2) * 512 + loff, &Kl[0][(sgk + c2) * 512]);
            gld16(Vsrc + (sgk + c2) * 512 + loff, &Vl[0][(sgk + c2) * 512]);
        }

        // ---- Q fragments (B-operand; lane = q col), pre-scaled ----
        bf16x8 qf[8];
        {
            const size_t rowoff = ((size_t)(b * S + qrow0 + ln) * H + h) * D;
            #pragma unroll
            for (int c = 0; c < 8; ++c) {
                float4 f0 = *(const float4*)(Q + rowoff + c * 16 + half * 8);
                float4 f1 = *(const float4*)(Q + rowoff + c * 16 + half * 8 + 4);
                unsigned int t[4];
                t[0] = pk2(f0.x * cfold, f0.y * cfold);
                t[1] = pk2(f0.z * cfold, f0.w * cfold);
                t[2] = pk2(f1.x * cfold, f1.y * cfold);
                t[3] = pk2(f1.z * cfold, f1.w * cfold);
                qf[c] = *(const bf16x8*)t;
            }
        }

        f32x16 o[4];
        #pragma unroll
        for (int dt = 0; dt < 4; ++dt)
            #pragma unroll
            for (int r = 0; r < 16; ++r) o[dt][r] = 0.0f;
        float l = 0.0f;

        asm volatile("s_waitcnt vmcnt(0)" ::: "memory");
        __builtin_amdgcn_s_barrier();

        int cur = 0;
        #pragma unroll 1
        for (int j = 0; j <= jmax; ++j) {
            // ---- issue next-tile staging first: latency hides under compute ----
            if (j < jmax) {
                const unsigned short* ks = Ksrc + (size_t)(j + 1) * TILE;
                const unsigned short* vs = Vsrc + (size_t)(j + 1) * TILE;
                #pragma unroll
                for (int c2 = 0; c2 < 2; ++c2) {
                    gld16(ks + (sgk + c2) * 512 + loff, &Kl[cur ^ 1][(sgk + c2) * 512]);
                    gld16(vs + (sgk + c2) * 512 + loff, &Vl[cur ^ 1][(sgk + c2) * 512]);
                }
            }

            // wave-uniform skip: this wave's k-half entirely above the diagonal?
            const bool wact = (!causal) || (j * 64 + nt * 32 <= qrow0 + 31);
            if (wact) {
                // ---- S^T = K Q^T for this wave's 32 k-rows ----
                f32x16 sacc;
                #pragma unroll
                for (int r = 0; r < 16; ++r) sacc[r] = 0.0f;
                const unsigned short* kl = &Kl[cur][nt * 4096 + kb];
                __builtin_amdgcn_s_setprio(1);
                #pragma unroll
                for (int c = 0; c < 8; ++c) {
                    uint4 raw = *(const uint4*)(kl + (((2 * c + half) ^ krho) << 3));
                    bf16x8 kf = *(const bf16x8*)&raw;
                    sacc = __builtin_amdgcn_mfma_f32_32x32x16_bf16(kf, qf[c], sacc, 0, 0, 0);
                }
                __builtin_amdgcn_s_setprio(0);

                // ---- in-register softmax numerator (no max-subtraction) ----
                float p[16];
                const int thr  = qrow0 + ln - j * 64;  // k_local <= thr allowed
                const bool full = (!causal) || (j * 64 + 63 <= qrow0);
                #pragma unroll
                for (int r = 0; r < 16; ++r) {
                    float e = __builtin_amdgcn_exp2f(sacc[r]);
                    if (!full) {
                        const int kl_ = nt * 32 + (r & 3) + 8 * (r >> 2) + 4 * half;
                        if (kl_ > thr) e = 0.0f;
                    }
                    l += e;
                    p[r] = e;
                }

                // ---- O^T(partial) += V^T P for this k-half ----
                __builtin_amdgcn_s_setprio(1);
                #pragma unroll
                for (int win2 = 0; win2 < 2; ++win2) {
                    unsigned int pw[4];
                    #pragma unroll
                    for (int d2 = 0; d2 < 4; ++d2)
                        pw[d2] = pk2(p[win2 * 8 + 2 * d2], p[win2 * 8 + 2 * d2 + 1]);
                    bf16x8 pf = *(const bf16x8*)pw;
                    const int cc = (nt * 2 + win2) * 2 + half;
                    const int voff = ((vrho * 8) + (cc ^ vrho)) << 3;
                    #pragma unroll
                    for (int dt = 0; dt < 4; ++dt) {
                        uint4 raw = *(const uint4*)(&Vl[cur][dt * 2048 + vg + voff]);
                        bf16x8 vf = *(const bf16x8*)&raw;
                        o[dt] = __builtin_amdgcn_mfma_f32_32x32x16_bf16(vf, pf, o[dt], 0, 0, 0);
                    }
                }
                __builtin_amdgcn_s_setprio(0);
            }

            // own 4 staging loads (issued at iter start) must have landed
            asm volatile("s_waitcnt vmcnt(0)" ::: "memory");
            __builtin_amdgcn_s_barrier();
            cur ^= 1;
        }

        // ---- merge k-halves (upper waves -> LDS, lower waves add) ----
        const float lp = l + __shfl_xor(l, 32);   // combine lane halves
        float* mb = mbf[qw];
        if (w >= 4) {
            #pragma unroll
            for (int dt = 0; dt < 2; ++dt)
                #pragma unroll
                for (int r = 0; r < 16; ++r)
                    mb[lane * 36 + dt * 16 + r] = o[dt][r];
            if (half == 0) lbf[qw][ln] = lp;
        }
        __syncthreads();
        float ltot = 1.0f;
        if (w < 4) {
            #pragma unroll
            for (int dt = 0; dt < 2; ++dt)
                #pragma unroll
                for (int r = 0; r < 16; ++r)
                    o[dt][r] += mb[lane * 36 + dt * 16 + r];
            ltot = lp + lbf[qw][ln];
        }
        __syncthreads();
        if (w >= 4) {
            #pragma unroll
            for (int dt = 2; dt < 4; ++dt)
                #pragma unroll
                for (int r = 0; r < 16; ++r)
                    mb[lane * 36 + (dt - 2) * 16 + r] = o[dt][r];
        }
        __syncthreads();
        if (w < 4) {
            #pragma unroll
            for (int dt = 2; dt < 4; ++dt)
                #pragma unroll
                for (int r = 0; r < 16; ++r)
                    o[dt][r] += mb[lane * 36 + (dt - 2) * 16 + r];

            // ---- epilogue: direct register->global store (lane = q row) ----
            const float inv = 1.0f / ltot;
            float* op = Op + ((size_t)(b * S + qrow0 + ln) * H + h) * D;
            #pragma unroll
            for (int dt = 0; dt < 4; ++dt)
                #pragma unroll
                for (int rq = 0; rq < 4; ++rq) {
                    float4 st;
                    st.x = o[dt][rq * 4 + 0] * inv;
                    st.y = o[dt][rq * 4 + 1] * inv;
                    st.z = o[dt][rq * 4 + 2] * inv;
                    st.w = o[dt][rq * 4 + 3] * inv;
                    *(float4*)(op + dt * 32 + 8 * rq + 4 * half) = st;
                }
        }
        __syncthreads();   // protect Kl/Vl before next phase's staging
    }
}

extern "C" void kernel_launch(void* const* d_in, const int* in_sizes, int n_in,
                              void* d_out, int out_size, void* d_ws, size_t ws_size,
                              hipStream_t stream) {
    const int B = in_sizes[0] / (S * H * D);   // expect 2
    unsigned short* Kb  = (unsigned short*)d_ws;
    unsigned short* Vtb = Kb + (size_t)B * S * H * D;

    cvt_kv<<<dim3(S / 64, B * H), 256, 0, stream>>>(
        (const float*)d_in[1], (const float*)d_in[2], Kb, Vtb);
    fa_fwd<<<dim3(8, B * H), 512, 0, stream>>>(
        (const float*)d_in[0], Kb, Vtb, (const int*)d_in[3], (float*)d_out);
}